// Round 1
// baseline (43.819 us; speedup 1.0000x reference)
//
#include <hip/hip_runtime.h>
#include <stdint.h>

#define BATCH 16384
#define KDIM  512
#define NDIM  1024
#define KW    16          // KDIM / 32 words per packed row
#define ROWS_PER_BLOCK 64

// Pack x (float32 0.0/1.0, [BATCH, KDIM]) into bits, 1 byte per thread.
// Byte t holds bits for elements [8t, 8t+8); little-endian byte order makes
// uint32 word i of row b hold bits k = 32i..32i+31 with bit j = x[b, 32i+j].
__global__ __launch_bounds__(256) void pack_x_kernel(const float* __restrict__ x,
                                                     uint8_t* __restrict__ xpb) {
    int t = blockIdx.x * 256 + threadIdx.x;           // one byte per thread
    const float4* xf = reinterpret_cast<const float4*>(x) + (size_t)t * 2;
    float4 a = xf[0];
    float4 b = xf[1];
    uint32_t byte = 0;
    byte |= (uint32_t)(a.x > 0.5f) << 0;
    byte |= (uint32_t)(a.y > 0.5f) << 1;
    byte |= (uint32_t)(a.z > 0.5f) << 2;
    byte |= (uint32_t)(a.w > 0.5f) << 3;
    byte |= (uint32_t)(b.x > 0.5f) << 4;
    byte |= (uint32_t)(b.y > 0.5f) << 5;
    byte |= (uint32_t)(b.z > 0.5f) << 6;
    byte |= (uint32_t)(b.w > 0.5f) << 7;
    xpb[t] = (uint8_t)byte;
}

// Pack G ([KDIM, NDIM] row-major, binary float) along K:
// Gt[i * NDIM + n] bit j = G[(32i + j), n].  Layout [i][n] so the main
// kernel's g[i] loads are coalesced across consecutive n.
__global__ __launch_bounds__(256) void pack_g_kernel(const float* __restrict__ G,
                                                     uint32_t* __restrict__ Gt) {
    int t = blockIdx.x * 256 + threadIdx.x;           // t = i*NDIM + n
    int n = t & (NDIM - 1);
    int i = t >> 10;                                  // NDIM = 1024
    uint32_t w = 0;
#pragma unroll
    for (int j = 0; j < 32; ++j) {
        w |= (uint32_t)(G[(size_t)(i * 32 + j) * NDIM + n] > 0.5f) << j;
    }
    Gt[t] = w;
}

// Main GF(2) GEMM: out[b, n] = parity(popcount over 16 words of xp[b] & g[n]).
// Thread owns column n; g[] lives in VGPRs for all ROWS_PER_BLOCK rows.
// xp row loads are wave-uniform (scalar-load eligible); stores coalesced.
__global__ __launch_bounds__(256) void gf2_gemm_kernel(const uint32_t* __restrict__ xp,
                                                       const uint32_t* __restrict__ Gt,
                                                       int* __restrict__ out) {
    int n = blockIdx.x * 256 + threadIdx.x;
    int row0 = blockIdx.y * ROWS_PER_BLOCK;

    uint32_t g[KW];
#pragma unroll
    for (int i = 0; i < KW; ++i) g[i] = Gt[i * NDIM + n];

#pragma unroll 4
    for (int r = 0; r < ROWS_PER_BLOCK; ++r) {
        int b = row0 + r;
        const uint4* xr = reinterpret_cast<const uint4*>(xp + (size_t)b * KW);
        uint4 x0 = xr[0];
        uint4 x1 = xr[1];
        uint4 x2 = xr[2];
        uint4 x3 = xr[3];
        // two accumulator chains for ILP
        uint32_t acc0 = __popc(x0.x & g[0])  + __popc(x0.y & g[1])
                      + __popc(x0.z & g[2])  + __popc(x0.w & g[3])
                      + __popc(x1.x & g[4])  + __popc(x1.y & g[5])
                      + __popc(x1.z & g[6])  + __popc(x1.w & g[7]);
        uint32_t acc1 = __popc(x2.x & g[8])  + __popc(x2.y & g[9])
                      + __popc(x2.z & g[10]) + __popc(x2.w & g[11])
                      + __popc(x3.x & g[12]) + __popc(x3.y & g[13])
                      + __popc(x3.z & g[14]) + __popc(x3.w & g[15]);
        out[(size_t)b * NDIM + n] = (int)((acc0 + acc1) & 1u);
    }
}

extern "C" void kernel_launch(void* const* d_in, const int* in_sizes, int n_in,
                              void* d_out, int out_size, void* d_ws, size_t ws_size,
                              hipStream_t stream) {
    const float* x = (const float*)d_in[0];       // [BATCH, KDIM] float32 (0/1)
    const float* G = (const float*)d_in[1];       // [KDIM, NDIM] float32 (0/1)
    int* out = (int*)d_out;                       // [BATCH, NDIM] int32

    // workspace layout: xp bits (1 MiB), then Gt (64 KiB)
    uint8_t*  xpb = (uint8_t*)d_ws;
    uint32_t* Gt  = (uint32_t*)((char*)d_ws + (size_t)BATCH * KW * 4);

    // pack x: BATCH*KDIM/8 bytes, one per thread
    pack_x_kernel<<<(BATCH * KDIM / 8) / 256, 256, 0, stream>>>(x, xpb);
    // pack G: KW*NDIM words, one per thread
    pack_g_kernel<<<(KW * NDIM) / 256, 256, 0, stream>>>(G, Gt);

    dim3 grid(NDIM / 256, BATCH / ROWS_PER_BLOCK);
    gf2_gemm_kernel<<<grid, 256, 0, stream>>>((const uint32_t*)xpb, Gt, out);
}